// Round 1
// 950.334 us; speedup vs baseline: 1.1557x; 1.1557x over previous
//
#include <hip/hip_runtime.h>
#include <hip/hip_bf16.h>

#define M_TOT 16384
#define N_TOT 4096
#define K_TOT 4096

typedef __attribute__((ext_vector_type(8))) short bf16x8;
typedef __attribute__((ext_vector_type(4))) float f32x4;

typedef const __attribute__((address_space(1))) void* gptr_t;
typedef __attribute__((address_space(3))) void* lptr_t;

__device__ inline unsigned short f2bf(float f) {
    union { float f; unsigned u; } v; v.f = f;
    unsigned u = v.u;
    u += 0x7FFFu + ((u >> 16) & 1u);   // RNE
    return (unsigned short)(u >> 16);
}

__device__ inline unsigned short sgn_bf(float f) {
    union { float f; unsigned u; } v; v.f = f;
    // bf16 +-1.0 : sign | 0x3F80
    return (unsigned short)(((v.u >> 16) & 0x8000u) | 0x3F80u);
}

// ---------------------------------------------------------------------------
// Kernel 1: per-row scale = mean(|W|), binarize W -> bf16 +-1
// ---------------------------------------------------------------------------
__global__ void prep_weight(const float* __restrict__ w,
                            unsigned short* __restrict__ bw,  // may be null
                            float* __restrict__ scale) {
    const int row = blockIdx.x;
    const int tid = threadIdx.x;
    const float4* wr = (const float4*)(w + (size_t)row * K_TOT);
    float s = 0.f;
#pragma unroll
    for (int i = 0; i < 4; ++i) {
        int idx = tid + i * 256;            // float4 index 0..1023
        float4 v = wr[idx];
        s += fabsf(v.x) + fabsf(v.y) + fabsf(v.z) + fabsf(v.w);
        if (bw) {
            ushort4 b;
            b.x = sgn_bf(v.x); b.y = sgn_bf(v.y);
            b.z = sgn_bf(v.z); b.w = sgn_bf(v.w);
            *(ushort4*)(bw + (size_t)row * K_TOT + idx * 4) = b;
        }
    }
#pragma unroll
    for (int off = 32; off > 0; off >>= 1) s += __shfl_down(s, off, 64);
    __shared__ float red[4];
    if ((tid & 63) == 0) red[tid >> 6] = s;
    __syncthreads();
    if (tid == 0) scale[row] = (red[0] + red[1] + red[2] + red[3]) * (1.f / (float)K_TOT);
}

// ---------------------------------------------------------------------------
// Kernel 2: x fp32 -> bf16
// ---------------------------------------------------------------------------
__global__ void conv_x(const float* __restrict__ x, unsigned short* __restrict__ xb) {
    const long n4 = (long)M_TOT * K_TOT / 4;
    long i = (long)blockIdx.x * blockDim.x + threadIdx.x;
    const long stride = (long)gridDim.x * blockDim.x;
    for (; i < n4; i += stride) {
        float4 v = ((const float4*)x)[i];
        ushort4 b;
        b.x = f2bf(v.x); b.y = f2bf(v.y); b.z = f2bf(v.z); b.w = f2bf(v.w);
        ((ushort4*)xb)[i] = b;
    }
}

// ---------------------------------------------------------------------------
// Kernel 3 (fast path): 256x256 8-phase GEMM (m201 template).
// 8 waves (2M x 4N), BK=64, 2 K-tiles per iteration, 8 phases/iter.
// LDS 128 KiB: [AS0 | BS0 | AS1 | BS1], each 256x64 bf16 (32 KiB).
// st_16x32 swizzle: byte ^= ((byte>>9)&1)<<5, applied as inverse-swizzled
// global SOURCE for global_load_lds (linear dest) + swizzled ds_read.
// Counted vmcnt(4) at phases 4/8 only; setprio(1) around MFMA clusters;
// bijective XCD blockIdx swizzle (nwg=1024 % 8 == 0).
// ---------------------------------------------------------------------------
#define AS0 0
#define BS0 16384
#define AS1 32768
#define BS1 49152

// stage one half-tile (128 rows x 64 cols) = 2 global_load_lds calls.
// LDS dest is linear; global source col is pre-swizzled (involution).
#define STAGE(Mat, row0, ldsbase, h, ktv)                                         \
  {                                                                               \
    _Pragma("unroll")                                                             \
    for (int c_ = 0; c_ < 2; ++c_) {                                              \
      const unsigned short* g_ = (Mat) +                                          \
          (size_t)((row0) + (h)*128 + c_*64 + wv*8 + srow) * K_TOT + (ktv) + scol;\
      __builtin_amdgcn_global_load_lds((gptr_t)g_,                                \
          (lptr_t)(lds + (ldsbase) + ((h)*128 + c_*64 + wv*8) * 64), 16, 0, 0);   \
    }                                                                             \
  }

// A fragments for M-half h: 8 x ds_read_b128 (swizzled addresses)
#define DS_A(h, base)                                                             \
  {                                                                               \
    _Pragma("unroll")                                                             \
    for (int i_ = 0; i_ < 4; ++i_) {                                              \
      _Pragma("unroll")                                                           \
      for (int k_ = 0; k_ < 2; ++k_) {                                            \
        int off_ = (wr*128 + (h)*64 + i_*16 + l16)*128 + k_*64 + quad*16;         \
        off_ ^= ((off_ >> 9) & 1) << 5;                                           \
        af[i_][k_] = *(const bf16x8*)((const char*)(lds + (base)) + off_);        \
      }                                                                           \
    }                                                                             \
  }

// B fragments for N-quarter pair g: 4 x ds_read_b128
#define DS_B(dst, g, base)                                                        \
  {                                                                               \
    _Pragma("unroll")                                                             \
    for (int j_ = 0; j_ < 2; ++j_) {                                              \
      _Pragma("unroll")                                                           \
      for (int k_ = 0; k_ < 2; ++k_) {                                            \
        int ob_ = (wc*64 + (g)*32 + j_*16 + l16)*128 + k_*64 + quad*16;           \
        ob_ ^= ((ob_ >> 9) & 1) << 5;                                             \
        dst[j_][k_] = *(const bf16x8*)((const char*)(lds + (base)) + ob_);        \
      }                                                                           \
    }                                                                             \
  }

// one C-quadrant x K=64 : 16 MFMA, setprio-wrapped
#define MMA(h, g, bset)                                                           \
  {                                                                               \
    __builtin_amdgcn_s_setprio(1);                                                \
    _Pragma("unroll")                                                             \
    for (int i_ = 0; i_ < 4; ++i_) {                                              \
      _Pragma("unroll")                                                           \
      for (int j_ = 0; j_ < 2; ++j_) {                                            \
        acc[(h)*4+i_][(g)*2+j_] = __builtin_amdgcn_mfma_f32_16x16x32_bf16(        \
            af[i_][0], bset[j_][0], acc[(h)*4+i_][(g)*2+j_], 0, 0, 0);            \
        acc[(h)*4+i_][(g)*2+j_] = __builtin_amdgcn_mfma_f32_16x16x32_bf16(        \
            af[i_][1], bset[j_][1], acc[(h)*4+i_][(g)*2+j_], 0, 0, 0);            \
      }                                                                           \
    }                                                                             \
    __builtin_amdgcn_s_setprio(0);                                                \
  }

#define BAR1  { __builtin_amdgcn_s_barrier(); asm volatile("s_waitcnt lgkmcnt(0)"); }
#define BAR2  { __builtin_amdgcn_s_barrier(); }
#define VM4   { asm volatile("s_waitcnt vmcnt(4)" ::: "memory"); }
#define VM0   { asm volatile("s_waitcnt vmcnt(0)" ::: "memory"); }

__global__ __launch_bounds__(512, 2) void gemm_bin_8ph(
    const unsigned short* __restrict__ A,
    const unsigned short* __restrict__ B,
    const float* __restrict__ scale,
    const float* __restrict__ bias,
    float* __restrict__ out) {
    __shared__ unsigned short lds[4 * 16384];   // 128 KiB

    const int tid  = threadIdx.x;
    const int wv   = tid >> 6;        // 0..7
    const int lane = tid & 63;
    const int quad = lane >> 4;
    const int l16  = lane & 15;
    const int wr   = wv >> 2;         // 0..1  (M)
    const int wc   = wv & 3;          // 0..3  (N)

    // XCD-aware bijective swizzle: nwg = 1024, 1024/8 = 128 per XCD
    int bid = blockIdx.x;
    bid = (bid & 7) * 128 + (bid >> 3);
    const int bn = (bid & 15) * 256;  // N_TOT/256 = 16
    const int bm = (bid >> 4) * 256;

    // staging lane -> (row, pre-swizzled col)
    const int srow = lane >> 3;                                     // 0..7
    const int scol = ((lane & 7) * 8) ^ (((lane >> 5) & 1) << 4);   // inverse st_16x32

    f32x4 acc[8][4] = {};
    bf16x8 af[4][2], bl[2][2], bh[2][2];

    // ---- prologue: tile0 A+B -> buf0, tile1 B -> buf1 (12 loads) ----
    STAGE(A, bm, AS0, 0, 0)
    STAGE(A, bm, AS0, 1, 0)
    STAGE(B, bn, BS0, 0, 0)
    STAGE(B, bn, BS0, 1, 0)
    STAGE(B, bn, BS1, 0, 64)
    STAGE(B, bn, BS1, 1, 64)
    asm volatile("s_waitcnt vmcnt(4)" ::: "memory");   // tile0 fully landed
    __builtin_amdgcn_s_barrier();

    int kt = 0;
#pragma unroll 1
    for (int t = 0; t < (K_TOT / 128) - 1; ++t, kt += 128) {
        // P0: read a(h0),b_lo of buf0; stage A->buf1 h0 @ kt+64
        DS_A(0, AS0) DS_B(bl, 0, BS0)
        STAGE(A, bm, AS1, 0, kt + 64)
        BAR1 MMA(0, 0, bl) BAR2
        // P1: read b_hi of buf0; stage A->buf1 h1
        DS_B(bh, 1, BS0)
        STAGE(A, bm, AS1, 1, kt + 64)
        BAR1 MMA(0, 1, bh) BAR2
        // P2: read a(h1) of buf0; stage B->buf0 h0 @ kt+128 (B buf0 free after P1)
        DS_A(1, AS0)
        STAGE(B, bn, BS0, 0, kt + 128)
        BAR1 MMA(1, 1, bh) BAR2
        // P3: stage B->buf0 h1; counted wait: buf1 tile ready (allow P2,P3 = 4)
        STAGE(B, bn, BS0, 1, kt + 128)
        BAR1 MMA(1, 0, bl) VM4 BAR2
        // P4: read a(h0),b_lo of buf1; stage A->buf0 h0 @ kt+128 (A buf0 free after P2)
        DS_A(0, AS1) DS_B(bl, 0, BS1)
        STAGE(A, bm, AS0, 0, kt + 128)
        BAR1 MMA(0, 0, bl) BAR2
        // P5: read b_hi of buf1; stage A->buf0 h1
        DS_B(bh, 1, BS1)
        STAGE(A, bm, AS0, 1, kt + 128)
        BAR1 MMA(0, 1, bh) BAR2
        // P6: read a(h1) of buf1; stage B->buf1 h0 @ kt+192 (B buf1 free after P5)
        DS_A(1, AS1)
        STAGE(B, bn, BS1, 0, kt + 192)
        BAR1 MMA(1, 1, bh) BAR2
        // P7: stage B->buf1 h1; counted wait: buf0 next tile ready (allow P6,P7 = 4)
        STAGE(B, bn, BS1, 1, kt + 192)
        BAR1 MMA(1, 0, bl) VM4 BAR2
    }

    // ---- peeled last iteration (kt = K_TOT-128): only A->buf1 staging ----
    DS_A(0, AS0) DS_B(bl, 0, BS0)
    STAGE(A, bm, AS1, 0, kt + 64)
    BAR1 MMA(0, 0, bl) BAR2
    DS_B(bh, 1, BS0)
    STAGE(A, bm, AS1, 1, kt + 64)
    BAR1 MMA(0, 1, bh) BAR2
    DS_A(1, AS0)
    BAR1 MMA(1, 1, bh) BAR2
    BAR1 MMA(1, 0, bl) VM0 BAR2      // drain: buf1 (A @P0/P1, B @prev P6/P7)
    DS_A(0, AS1) DS_B(bl, 0, BS1)
    BAR1 MMA(0, 0, bl) BAR2
    DS_B(bh, 1, BS1)
    BAR1 MMA(0, 1, bh) BAR2
    DS_A(1, AS1)
    BAR1 MMA(1, 1, bh) BAR2
    BAR1 MMA(1, 0, bl)

    // ---- epilogue: C/D layout col=l16, row=quad*4+reg (verified m89/m91) ----
#pragma unroll
    for (int j4 = 0; j4 < 4; ++j4) {
        const int gn = bn + wc * 64 + j4 * 16 + l16;
        const float sc = scale[gn];
        const float bi = bias[gn];
#pragma unroll
        for (int i8 = 0; i8 < 8; ++i8) {
            const int gm0 = bm + wr * 128 + i8 * 16 + quad * 4;
#pragma unroll
            for (int r = 0; r < 4; ++r)
                out[(size_t)(gm0 + r) * N_TOT + gn] = acc[i8][j4][r] * sc + bi;
        }
    }
}

// ---------------------------------------------------------------------------
// Fallback (ws too small): fp32 inputs, inline convert, padded LDS
// ---------------------------------------------------------------------------
__global__ __launch_bounds__(256) void gemm_bin_fb(const float* __restrict__ A,
                                                   const float* __restrict__ Bf,
                                                   const float* __restrict__ scale,
                                                   const float* __restrict__ bias,
                                                   float* __restrict__ out) {
    __shared__ unsigned short As[128][40];
    __shared__ unsigned short Bs[128][40];

    const int tid  = threadIdx.x;
    const int wave = tid >> 6;
    const int lane = tid & 63;
    const int quad = lane >> 4;
    const int l16  = lane & 15;
    const int wr   = wave >> 1;
    const int wc   = wave & 1;
    const int bn   = blockIdx.x * 128;
    const int bm   = blockIdx.y * 128;

    f32x4 acc[4][4] = {};

    for (int kt = 0; kt < K_TOT; kt += 32) {
        const int row0 = tid >> 3;
        const int c4   = (tid & 7) * 4;
#pragma unroll
        for (int p = 0; p < 4; ++p) {
            int row = row0 + p * 32;
            float4 v = *(const float4*)(A + (size_t)(bm + row) * K_TOT + kt + c4);
            ushort4 b;
            b.x = f2bf(v.x); b.y = f2bf(v.y); b.z = f2bf(v.z); b.w = f2bf(v.w);
            *(ushort4*)&As[row][c4] = b;
        }
#pragma unroll
        for (int p = 0; p < 4; ++p) {
            int row = row0 + p * 32;
            float4 v = *(const float4*)(Bf + (size_t)(bn + row) * K_TOT + kt + c4);
            ushort4 b;
            b.x = sgn_bf(v.x); b.y = sgn_bf(v.y); b.z = sgn_bf(v.z); b.w = sgn_bf(v.w);
            *(ushort4*)&Bs[row][c4] = b;
        }
        __syncthreads();

        bf16x8 af2[4], bfr[4];
#pragma unroll
        for (int i = 0; i < 4; ++i)
            af2[i] = *(const bf16x8*)&As[wr * 64 + i * 16 + l16][quad * 8];
#pragma unroll
        for (int j = 0; j < 4; ++j)
            bfr[j] = *(const bf16x8*)&Bs[wc * 64 + j * 16 + l16][quad * 8];
#pragma unroll
        for (int i = 0; i < 4; ++i)
#pragma unroll
            for (int j = 0; j < 4; ++j)
                acc[i][j] = __builtin_amdgcn_mfma_f32_16x16x32_bf16(af2[i], bfr[j], acc[i][j], 0, 0, 0);
        __syncthreads();
    }

#pragma unroll
    for (int j = 0; j < 4; ++j) {
        const int gn = bn + wc * 64 + j * 16 + l16;
        const float sc = scale[gn];
        const float bi = bias[gn];
#pragma unroll
        for (int i = 0; i < 4; ++i) {
            const int gm0 = bm + wr * 64 + i * 16 + quad * 4;
#pragma unroll
            for (int r = 0; r < 4; ++r)
                out[(size_t)(gm0 + r) * N_TOT + gn] = acc[i][j][r] * sc + bi;
        }
    }
}

// ---------------------------------------------------------------------------
extern "C" void kernel_launch(void* const* d_in, const int* in_sizes, int n_in,
                              void* d_out, int out_size, void* d_ws, size_t ws_size,
                              hipStream_t stream) {
    const float* x    = (const float*)d_in[0];
    const float* w    = (const float*)d_in[1];
    const float* bias = (const float*)d_in[2];
    float* out        = (float*)d_out;

    // ws layout: [scale 16KB][bw 32MB][xb 128MB]
    const size_t off_scale = 0;
    const size_t off_bw    = 16384;
    const size_t off_xb    = off_bw + (size_t)N_TOT * K_TOT * 2;
    const size_t need_full = off_xb + (size_t)M_TOT * K_TOT * 2;

    float* scale = (float*)((char*)d_ws + off_scale);
    const bool full = ws_size >= need_full;

    if (full) {
        unsigned short* bw = (unsigned short*)((char*)d_ws + off_bw);
        unsigned short* xb = (unsigned short*)((char*)d_ws + off_xb);
        prep_weight<<<N_TOT, 256, 0, stream>>>(w, bw, scale);
        conv_x<<<8192, 256, 0, stream>>>(x, xb);
        const int nwg = (M_TOT / 256) * (N_TOT / 256);   // 64 * 16 = 1024
        gemm_bin_8ph<<<nwg, 512, 0, stream>>>(xb, bw, scale, bias, out);
    } else {
        prep_weight<<<N_TOT, 256, 0, stream>>>(w, nullptr, scale);
        dim3 grid(N_TOT / 128, M_TOT / 128);
        gemm_bin_fb<<<grid, 256, 0, stream>>>(x, w, scale, bias, out);
    }
}

// Round 2
// 894.829 us; speedup vs baseline: 1.2274x; 1.0620x over previous
//
#include <hip/hip_runtime.h>
#include <hip/hip_bf16.h>

#define M_TOT 16384
#define N_TOT 4096
#define K_TOT 4096

typedef __attribute__((ext_vector_type(8))) short bf16x8;
typedef __attribute__((ext_vector_type(4))) float f32x4;

typedef const __attribute__((address_space(1))) void* gptr_t;
typedef __attribute__((address_space(3))) void* lptr_t;

__device__ inline unsigned short f2bf(float f) {
    union { float f; unsigned u; } v; v.f = f;
    unsigned u = v.u;
    u += 0x7FFFu + ((u >> 16) & 1u);   // RNE
    return (unsigned short)(u >> 16);
}

__device__ inline unsigned short sgn_bf(float f) {
    union { float f; unsigned u; } v; v.f = f;
    // bf16 +-1.0 : sign | 0x3F80
    return (unsigned short)(((v.u >> 16) & 0x8000u) | 0x3F80u);
}

// ---------------------------------------------------------------------------
// Kernel 1: per-row scale = mean(|W|), binarize W -> bf16 +-1
// ---------------------------------------------------------------------------
__global__ void prep_weight(const float* __restrict__ w,
                            unsigned short* __restrict__ bw,  // may be null
                            float* __restrict__ scale) {
    const int row = blockIdx.x;
    const int tid = threadIdx.x;
    const float4* wr = (const float4*)(w + (size_t)row * K_TOT);
    float s = 0.f;
#pragma unroll
    for (int i = 0; i < 4; ++i) {
        int idx = tid + i * 256;            // float4 index 0..1023
        float4 v = wr[idx];
        s += fabsf(v.x) + fabsf(v.y) + fabsf(v.z) + fabsf(v.w);
        if (bw) {
            ushort4 b;
            b.x = sgn_bf(v.x); b.y = sgn_bf(v.y);
            b.z = sgn_bf(v.z); b.w = sgn_bf(v.w);
            *(ushort4*)(bw + (size_t)row * K_TOT + idx * 4) = b;
        }
    }
#pragma unroll
    for (int off = 32; off > 0; off >>= 1) s += __shfl_down(s, off, 64);
    __shared__ float red[4];
    if ((tid & 63) == 0) red[tid >> 6] = s;
    __syncthreads();
    if (tid == 0) scale[row] = (red[0] + red[1] + red[2] + red[3]) * (1.f / (float)K_TOT);
}

// ---------------------------------------------------------------------------
// Kernel 2: x fp32 -> bf16
// ---------------------------------------------------------------------------
__global__ void conv_x(const float* __restrict__ x, unsigned short* __restrict__ xb) {
    const long n4 = (long)M_TOT * K_TOT / 4;
    long i = (long)blockIdx.x * blockDim.x + threadIdx.x;
    const long stride = (long)gridDim.x * blockDim.x;
    for (; i < n4; i += stride) {
        float4 v = ((const float4*)x)[i];
        ushort4 b;
        b.x = f2bf(v.x); b.y = f2bf(v.y); b.z = f2bf(v.z); b.w = f2bf(v.w);
        ((ushort4*)xb)[i] = b;
    }
}

// ---------------------------------------------------------------------------
// Kernel 3 (fast path): 256x256 8-phase GEMM (m201 template).
// 8 waves (2M x 4N), BK=64, 2 K-tiles per iteration, 8 phases/iter.
// LDS 128 KiB: [AS0 | BS0 | AS1 | BS1], each 256x64 bf16 (32 KiB).
// Swizzle (Guideline-4 form, 3-bit): byte ^= ((byte>>7)&7)<<4 — XORs row
// bits 0-2 into the 16B-slot index, spreading the 16 same-slot lanes of a
// ds_read_b128 across all 8 slots of the 128B line (provably conflict-free
// for this fragment pattern). Applied as inverse-swizzled global SOURCE for
// global_load_lds (linear dest, involution within each 8-row group) +
// swizzled ds_read address.
// Counted vmcnt(4) at phases 4/8 only; setprio(1) around MFMA clusters;
// bijective XCD blockIdx swizzle (nwg=1024 % 8 == 0).
// ---------------------------------------------------------------------------
#define AS0 0
#define BS0 16384
#define AS1 32768
#define BS1 49152

// stage one half-tile (128 rows x 64 cols) = 2 global_load_lds calls.
// LDS dest is linear; global source col is pre-swizzled (involution).
#define STAGE(Mat, row0, ldsbase, h, ktv)                                         \
  {                                                                               \
    _Pragma("unroll")                                                             \
    for (int c_ = 0; c_ < 2; ++c_) {                                              \
      const unsigned short* g_ = (Mat) +                                          \
          (size_t)((row0) + (h)*128 + c_*64 + wv*8 + srow) * K_TOT + (ktv) + scol;\
      __builtin_amdgcn_global_load_lds((gptr_t)g_,                                \
          (lptr_t)(lds + (ldsbase) + ((h)*128 + c_*64 + wv*8) * 64), 16, 0, 0);   \
    }                                                                             \
  }

// A fragments for M-half h: 8 x ds_read_b128 (swizzled addresses)
#define DS_A(h, base)                                                             \
  {                                                                               \
    _Pragma("unroll")                                                             \
    for (int i_ = 0; i_ < 4; ++i_) {                                              \
      _Pragma("unroll")                                                           \
      for (int k_ = 0; k_ < 2; ++k_) {                                            \
        int off_ = (wr*128 + (h)*64 + i_*16 + l16)*128 + k_*64 + quad*16;         \
        off_ ^= ((off_ >> 7) & 7) << 4;                                           \
        af[i_][k_] = *(const bf16x8*)((const char*)(lds + (base)) + off_);        \
      }                                                                           \
    }                                                                             \
  }

// B fragments for N-quarter pair g: 4 x ds_read_b128
#define DS_B(dst, g, base)                                                        \
  {                                                                               \
    _Pragma("unroll")                                                             \
    for (int j_ = 0; j_ < 2; ++j_) {                                              \
      _Pragma("unroll")                                                           \
      for (int k_ = 0; k_ < 2; ++k_) {                                            \
        int ob_ = (wc*64 + (g)*32 + j_*16 + l16)*128 + k_*64 + quad*16;           \
        ob_ ^= ((ob_ >> 7) & 7) << 4;                                             \
        dst[j_][k_] = *(const bf16x8*)((const char*)(lds + (base)) + ob_);        \
      }                                                                           \
    }                                                                             \
  }

// one C-quadrant x K=64 : 16 MFMA, setprio-wrapped
#define MMA(h, g, bset)                                                           \
  {                                                                               \
    __builtin_amdgcn_s_setprio(1);                                                \
    _Pragma("unroll")                                                             \
    for (int i_ = 0; i_ < 4; ++i_) {                                              \
      _Pragma("unroll")                                                           \
      for (int j_ = 0; j_ < 2; ++j_) {                                            \
        acc[(h)*4+i_][(g)*2+j_] = __builtin_amdgcn_mfma_f32_16x16x32_bf16(        \
            af[i_][0], bset[j_][0], acc[(h)*4+i_][(g)*2+j_], 0, 0, 0);            \
        acc[(h)*4+i_][(g)*2+j_] = __builtin_amdgcn_mfma_f32_16x16x32_bf16(        \
            af[i_][1], bset[j_][1], acc[(h)*4+i_][(g)*2+j_], 0, 0, 0);            \
      }                                                                           \
    }                                                                             \
    __builtin_amdgcn_s_setprio(0);                                                \
  }

#define BAR1  { __builtin_amdgcn_s_barrier(); asm volatile("s_waitcnt lgkmcnt(0)"); }
#define BAR2  { __builtin_amdgcn_s_barrier(); }
#define VM4   { asm volatile("s_waitcnt vmcnt(4)" ::: "memory"); }
#define VM0   { asm volatile("s_waitcnt vmcnt(0)" ::: "memory"); }

__global__ __launch_bounds__(512, 2) void gemm_bin_8ph(
    const unsigned short* __restrict__ A,
    const unsigned short* __restrict__ B,
    const float* __restrict__ scale,
    const float* __restrict__ bias,
    float* __restrict__ out) {
    __shared__ unsigned short lds[4 * 16384];   // 128 KiB

    const int tid  = threadIdx.x;
    const int wv   = tid >> 6;        // 0..7
    const int lane = tid & 63;
    const int quad = lane >> 4;
    const int l16  = lane & 15;
    const int wr   = wv >> 2;         // 0..1  (M)
    const int wc   = wv & 3;          // 0..3  (N)

    // XCD-aware bijective swizzle: nwg = 1024, 1024/8 = 128 per XCD
    int bid = blockIdx.x;
    bid = (bid & 7) * 128 + (bid >> 3);
    const int bn = (bid & 15) * 256;  // N_TOT/256 = 16
    const int bm = (bid >> 4) * 256;

    // staging lane -> (row, pre-swizzled col): inverse of the 3-bit XOR.
    // lane l writes LDS slot (l&7) of row (l>>3); it must carry the data of
    // unswizzled slot (l&7)^((l>>3)&7)  (involution within the 8-row group).
    const int srow = lane >> 3;                                     // 0..7
    const int scol = (((lane & 7) ^ ((lane >> 3) & 7)) * 8);        // elements

    f32x4 acc[8][4] = {};
    bf16x8 af[4][2], bl[2][2], bh[2][2];

    // ---- prologue: tile0 A+B -> buf0, tile1 B -> buf1 (12 loads) ----
    STAGE(A, bm, AS0, 0, 0)
    STAGE(A, bm, AS0, 1, 0)
    STAGE(B, bn, BS0, 0, 0)
    STAGE(B, bn, BS0, 1, 0)
    STAGE(B, bn, BS1, 0, 64)
    STAGE(B, bn, BS1, 1, 64)
    asm volatile("s_waitcnt vmcnt(4)" ::: "memory");   // tile0 fully landed
    __builtin_amdgcn_s_barrier();

    int kt = 0;
#pragma unroll 1
    for (int t = 0; t < (K_TOT / 128) - 1; ++t, kt += 128) {
        // P0: read a(h0),b_lo of buf0; stage A->buf1 h0 @ kt+64
        DS_A(0, AS0) DS_B(bl, 0, BS0)
        STAGE(A, bm, AS1, 0, kt + 64)
        BAR1 MMA(0, 0, bl) BAR2
        // P1: read b_hi of buf0; stage A->buf1 h1
        DS_B(bh, 1, BS0)
        STAGE(A, bm, AS1, 1, kt + 64)
        BAR1 MMA(0, 1, bh) BAR2
        // P2: read a(h1) of buf0; stage B->buf0 h0 @ kt+128 (B buf0 free after P1)
        DS_A(1, AS0)
        STAGE(B, bn, BS0, 0, kt + 128)
        BAR1 MMA(1, 1, bh) BAR2
        // P3: stage B->buf0 h1; counted wait: buf1 tile ready (allow P2,P3 = 4)
        STAGE(B, bn, BS0, 1, kt + 128)
        BAR1 MMA(1, 0, bl) VM4 BAR2
        // P4: read a(h0),b_lo of buf1; stage A->buf0 h0 @ kt+128 (A buf0 free after P2)
        DS_A(0, AS1) DS_B(bl, 0, BS1)
        STAGE(A, bm, AS0, 0, kt + 128)
        BAR1 MMA(0, 0, bl) BAR2
        // P5: read b_hi of buf1; stage A->buf0 h1
        DS_B(bh, 1, BS1)
        STAGE(A, bm, AS0, 1, kt + 128)
        BAR1 MMA(0, 1, bh) BAR2
        // P6: read a(h1) of buf1; stage B->buf1 h0 @ kt+192 (B buf1 free after P5)
        DS_A(1, AS1)
        STAGE(B, bn, BS1, 0, kt + 192)
        BAR1 MMA(1, 1, bh) BAR2
        // P7: stage B->buf1 h1; counted wait: buf0 next tile ready (allow P6,P7 = 4)
        STAGE(B, bn, BS1, 1, kt + 192)
        BAR1 MMA(1, 0, bl) VM4 BAR2
    }

    // ---- peeled last iteration (kt = K_TOT-128): only A->buf1 staging ----
    DS_A(0, AS0) DS_B(bl, 0, BS0)
    STAGE(A, bm, AS1, 0, kt + 64)
    BAR1 MMA(0, 0, bl) BAR2
    DS_B(bh, 1, BS0)
    STAGE(A, bm, AS1, 1, kt + 64)
    BAR1 MMA(0, 1, bh) BAR2
    DS_A(1, AS0)
    BAR1 MMA(1, 1, bh) BAR2
    BAR1 MMA(1, 0, bl) VM0 BAR2      // drain: buf1 (A @P0/P1, B @prev P6/P7)
    DS_A(0, AS1) DS_B(bl, 0, BS1)
    BAR1 MMA(0, 0, bl) BAR2
    DS_B(bh, 1, BS1)
    BAR1 MMA(0, 1, bh) BAR2
    DS_A(1, AS1)
    BAR1 MMA(1, 1, bh) BAR2
    BAR1 MMA(1, 0, bl)

    // ---- epilogue: C/D layout col=l16, row=quad*4+reg (verified m89/m91) ----
#pragma unroll
    for (int j4 = 0; j4 < 4; ++j4) {
        const int gn = bn + wc * 64 + j4 * 16 + l16;
        const float sc = scale[gn];
        const float bi = bias[gn];
#pragma unroll
        for (int i8 = 0; i8 < 8; ++i8) {
            const int gm0 = bm + wr * 128 + i8 * 16 + quad * 4;
#pragma unroll
            for (int r = 0; r < 4; ++r)
                out[(size_t)(gm0 + r) * N_TOT + gn] = acc[i8][j4][r] * sc + bi;
        }
    }
}

// ---------------------------------------------------------------------------
// Fallback (ws too small): fp32 inputs, inline convert, padded LDS
// ---------------------------------------------------------------------------
__global__ __launch_bounds__(256) void gemm_bin_fb(const float* __restrict__ A,
                                                   const float* __restrict__ Bf,
                                                   const float* __restrict__ scale,
                                                   const float* __restrict__ bias,
                                                   float* __restrict__ out) {
    __shared__ unsigned short As[128][40];
    __shared__ unsigned short Bs[128][40];

    const int tid  = threadIdx.x;
    const int wave = tid >> 6;
    const int lane = tid & 63;
    const int quad = lane >> 4;
    const int l16  = lane & 15;
    const int wr   = wave >> 1;
    const int wc   = wave & 1;
    const int bn   = blockIdx.x * 128;
    const int bm   = blockIdx.y * 128;

    f32x4 acc[4][4] = {};

    for (int kt = 0; kt < K_TOT; kt += 32) {
        const int row0 = tid >> 3;
        const int c4   = (tid & 7) * 4;
#pragma unroll
        for (int p = 0; p < 4; ++p) {
            int row = row0 + p * 32;
            float4 v = *(const float4*)(A + (size_t)(bm + row) * K_TOT + kt + c4);
            ushort4 b;
            b.x = f2bf(v.x); b.y = f2bf(v.y); b.z = f2bf(v.z); b.w = f2bf(v.w);
            *(ushort4*)&As[row][c4] = b;
        }
#pragma unroll
        for (int p = 0; p < 4; ++p) {
            int row = row0 + p * 32;
            float4 v = *(const float4*)(Bf + (size_t)(bn + row) * K_TOT + kt + c4);
            ushort4 b;
            b.x = sgn_bf(v.x); b.y = sgn_bf(v.y);
            b.z = sgn_bf(v.z); b.w = sgn_bf(v.w);
            *(ushort4*)&Bs[row][c4] = b;
        }
        __syncthreads();

        bf16x8 af2[4], bfr[4];
#pragma unroll
        for (int i = 0; i < 4; ++i)
            af2[i] = *(const bf16x8*)&As[wr * 64 + i * 16 + l16][quad * 8];
#pragma unroll
        for (int j = 0; j < 4; ++j)
            bfr[j] = *(const bf16x8*)&Bs[wc * 64 + j * 16 + l16][quad * 8];
#pragma unroll
        for (int i = 0; i < 4; ++i)
#pragma unroll
            for (int j = 0; j < 4; ++j)
                acc[i][j] = __builtin_amdgcn_mfma_f32_16x16x32_bf16(af2[i], bfr[j], acc[i][j], 0, 0, 0);
        __syncthreads();
    }

#pragma unroll
    for (int j = 0; j < 4; ++j) {
        const int gn = bn + wc * 64 + j * 16 + l16;
        const float sc = scale[gn];
        const float bi = bias[gn];
#pragma unroll
        for (int i = 0; i < 4; ++i) {
            const int gm0 = bm + wr * 64 + i * 16 + quad * 4;
#pragma unroll
            for (int r = 0; r < 4; ++r)
                out[(size_t)(gm0 + r) * N_TOT + gn] = acc[i][j][r] * sc + bi;
        }
    }
}

// ---------------------------------------------------------------------------
extern "C" void kernel_launch(void* const* d_in, const int* in_sizes, int n_in,
                              void* d_out, int out_size, void* d_ws, size_t ws_size,
                              hipStream_t stream) {
    const float* x    = (const float*)d_in[0];
    const float* w    = (const float*)d_in[1];
    const float* bias = (const float*)d_in[2];
    float* out        = (float*)d_out;

    // ws layout: [scale 16KB][bw 32MB][xb 128MB]
    const size_t off_scale = 0;
    const size_t off_bw    = 16384;
    const size_t off_xb    = off_bw + (size_t)N_TOT * K_TOT * 2;
    const size_t need_full = off_xb + (size_t)M_TOT * K_TOT * 2;

    float* scale = (float*)((char*)d_ws + off_scale);
    const bool full = ws_size >= need_full;

    if (full) {
        unsigned short* bw = (unsigned short*)((char*)d_ws + off_bw);
        unsigned short* xb = (unsigned short*)((char*)d_ws + off_xb);
        prep_weight<<<N_TOT, 256, 0, stream>>>(w, bw, scale);
        conv_x<<<8192, 256, 0, stream>>>(x, xb);
        const int nwg = (M_TOT / 256) * (N_TOT / 256);   // 64 * 16 = 1024
        gemm_bin_8ph<<<nwg, 512, 0, stream>>>(xb, bw, scale, bias, out);
    } else {
        prep_weight<<<N_TOT, 256, 0, stream>>>(w, nullptr, scale);
        dim3 grid(N_TOT / 128, M_TOT / 128);
        gemm_bin_fb<<<grid, 256, 0, stream>>>(x, w, scale, bias, out);
    }
}